// Round 3
// baseline (871.024 us; speedup 1.0000x reference)
//
#include <hip/hip_runtime.h>

// Loihi SNN, 3 layers of (GEMM -> Loihi scan -> delay), MFMA edition.
//
// Exact-fp32-via-bf16: spikes are {0,1} (exact in bf16); W splits EXACTLY
// into 3 bf16 planes (hi/mid/lo). GEMM = 3 bf16 MFMA passes accumulated in
// one fp32 acc.
//
// Round 3: K-split across blockIdx.z (vis x3, combi x4) with deterministic
// partial buffers to fix grid-size-bound occupancy (was 400 blocks = 1.56
// blocks/CU, 18.5% occupancy). Scans sum the partials in fixed order.
//
// Layouts:
//   S   (GEMM B operand): [nt = n*400+t][Kpad] bf16(u16), contiguous K
//   W3  (GEMM A operand): 3 planes [C][Kpad] bf16(u16)
//   X   (GEMM out):       [z][nt][C] fp32 partials -> scans sum + read coalesced
//   out:                  [n][c][t] fp32 (reference layout)

typedef unsigned short u16;
typedef unsigned int u32;
typedef __attribute__((ext_vector_type(8))) short short8;
typedef __attribute__((ext_vector_type(4))) float f32x4;

#define GLOAD16(g, l)                                                         \
    __builtin_amdgcn_global_load_lds(                                         \
        (const __attribute__((address_space(1))) u32*)(g),                    \
        (__attribute__((address_space(3))) u32*)(l), 16, 0, 0)

__device__ __forceinline__ u16 f2bf_trunc(float x) {
    return (u16)(__float_as_uint(x) >> 16);
}

// ---------------- W -> 3 exact bf16 planes ----------------
__global__ void split_w(const float* __restrict__ W,
                        u16* __restrict__ Wh, u16* __restrict__ Wm,
                        u16* __restrict__ Wl, int K, int Kpad)
{
    const int c = blockIdx.y;
    const int k = blockIdx.x * 256 + threadIdx.x;
    if (k >= Kpad) return;
    float w = (k < K) ? W[(size_t)c * K + k] : 0.f;
    u32 b  = __float_as_uint(w);
    u32 hb = b & 0xFFFF0000u;
    float r  = w - __uint_as_float(hb);
    u32 mb = __float_as_uint(r) & 0xFFFF0000u;
    float r2 = r - __uint_as_float(mb);
    u32 lb = __float_as_uint(r2) & 0xFFFF0000u;
    size_t o = (size_t)c * Kpad + k;
    Wh[o] = (u16)(hb >> 16);
    Wm[o] = (u16)(mb >> 16);
    Wl[o] = (u16)(lb >> 16);
}

// ------- spikes fp32 [n][I][400] -> bf16 [n*400+t][Kpad] (transpose) -------
__global__ __launch_bounds__(256) void cvt_sp(const float* __restrict__ S,
                                              u16* __restrict__ Sp,
                                              int I, int Kpad)
{
    __shared__ u16 tile[64][80];   // [t][i], stride 160B (16B-aligned rows)
    const int n  = blockIdx.z;
    const int i0 = blockIdx.y * 64;
    const int t0 = blockIdx.x * 64;
    const int tid = threadIdx.x;

    const int il = tid >> 2;       // 0..63 input row (i)
    const int tq = tid & 3;
    const int gi = i0 + il;
    const bool iok = gi < I;
    const float* srow = S + ((size_t)n * I + gi) * 400 + t0;

    #pragma unroll
    for (int s = 0; s < 4; ++s) {
        const int tl = tq * 16 + s * 4;
        float4 v = make_float4(0.f, 0.f, 0.f, 0.f);
        if (iok && (t0 + tl) < 400)
            v = *(const float4*)(srow + tl);
        tile[tl + 0][il] = f2bf_trunc(v.x);
        tile[tl + 1][il] = f2bf_trunc(v.y);
        tile[tl + 2][il] = f2bf_trunc(v.z);
        tile[tl + 3][il] = f2bf_trunc(v.w);
    }
    __syncthreads();

    const int tl = tid >> 2;       // 0..63 output row (t)
    const int iq = tid & 3;        // 16-wide i chunk
    const int t  = t0 + tl;
    const int go = i0 + iq * 16;
    if (t < 400 && go < Kpad) {
        u16* dst = Sp + (size_t)(n * 400 + t) * Kpad + go;
        *(short8*)(dst)     = *(const short8*)&tile[tl][iq * 16];
        *(short8*)(dst + 8) = *(const short8*)&tile[tl][iq * 16 + 8];
    }
}

// ---------------- 3-plane bf16 MFMA GEMM, K-split ----------------
// Xp[z][nt][c] = sum_{k in chunk z} (Wh+Wm+Wl)[c][k] * S[nt][k]
// 128x128 tile, BK=32, 4 waves (2x2), wave = 64x64 = 4x4 MFMA tiles.
__global__ __launch_bounds__(256) void gemm3(
    const u16* __restrict__ Wh, const u16* __restrict__ Wm,
    const u16* __restrict__ Wl, const u16* __restrict__ S,
    float* __restrict__ Xp, int C, int Kpad, int chunkIters)
{
    __shared__ u16 lds[4 * 4096];   // A planes 0..2, B at 3*4096 ([128][32] each)

    const int tid  = threadIdx.x;
    const int lane = tid & 63, wave = tid >> 6;
    const int c0  = blockIdx.y * 128;
    const int nt0 = blockIdx.x * 128;
    const int NT  = gridDim.x * 128;

    const int kz0 = blockIdx.z * chunkIters * 32;
    const int kz1 = min(Kpad, kz0 + chunkIters * 32);
    float* __restrict__ X = Xp + (size_t)blockIdx.z * NT * C;

    // staging: per wave 2 chunks per tile; chunk = 16 rows x 32 k (1KB)
    const int ch0 = wave * 2, ch1 = ch0 + 1;
    const int lrow = lane >> 2;          // row within chunk
    const int lk   = (lane & 3) * 8;     // u16 offset within row
    const size_t aoff0 = (size_t)(c0 + ch0 * 16 + lrow) * Kpad + lk;
    const size_t aoff1 = (size_t)(c0 + ch1 * 16 + lrow) * Kpad + lk;
    const size_t boff0 = (size_t)(nt0 + ch0 * 16 + lrow) * Kpad + lk;
    const size_t boff1 = (size_t)(nt0 + ch1 * 16 + lrow) * Kpad + lk;

    const int l15 = lane & 15, l16 = lane >> 4;
    const int wm = wave >> 1, wn = wave & 1;
    const int aBase = (wm * 64 + l15) * 32 + l16 * 8;            // + p*4096 + mi*512
    const int bBase = 3 * 4096 + (wn * 64 + l15) * 32 + l16 * 8; // + ni*512

    f32x4 acc[4][4];
    #pragma unroll
    for (int i = 0; i < 4; ++i)
        #pragma unroll
        for (int j = 0; j < 4; ++j)
            acc[i][j] = {0.f, 0.f, 0.f, 0.f};

    const u16* Wp[3] = {Wh, Wm, Wl};

    for (int k0 = kz0; k0 < kz1; k0 += 32) {
        #pragma unroll
        for (int p = 0; p < 3; ++p) {
            GLOAD16(Wp[p] + aoff0 + k0, &lds[p * 4096 + ch0 * 512]);
            GLOAD16(Wp[p] + aoff1 + k0, &lds[p * 4096 + ch1 * 512]);
        }
        GLOAD16(S + boff0 + k0, &lds[3 * 4096 + ch0 * 512]);
        GLOAD16(S + boff1 + k0, &lds[3 * 4096 + ch1 * 512]);
        __syncthreads();   // drains vmcnt -> staged data visible

        short8 bf[4];
        #pragma unroll
        for (int ni = 0; ni < 4; ++ni)
            bf[ni] = *(const short8*)&lds[bBase + ni * 512];
        #pragma unroll
        for (int mi = 0; mi < 4; ++mi) {
            #pragma unroll
            for (int p = 0; p < 3; ++p) {
                short8 af = *(const short8*)&lds[p * 4096 + aBase + mi * 512];
                #pragma unroll
                for (int ni = 0; ni < 4; ++ni)
                    acc[mi][ni] = __builtin_amdgcn_mfma_f32_16x16x32_bf16(
                        af, bf[ni], acc[mi][ni], 0, 0, 0);
            }
        }
        __syncthreads();   // readers done before next overwrite
    }

    // epilogue: D row=(l16*4+r) -> c, col=l15 -> nt ; 4 consecutive c = float4
    #pragma unroll
    for (int mi = 0; mi < 4; ++mi) {
        const int c = c0 + wm * 64 + mi * 16 + l16 * 4;
        #pragma unroll
        for (int ni = 0; ni < 4; ++ni) {
            const int nt = nt0 + wn * 64 + ni * 16 + l15;
            *(f32x4*)&X[(size_t)nt * C + c] = acc[mi][ni];
        }
    }
}

// ---------------- Loihi scans (8-deep pipelined loads) ----------------
// scan_ab: layer-1 tact (1 partial) + layer-1 vis (3 partials) -> combi spikes
__global__ __launch_bounds__(256) void scan_ab(const float* __restrict__ Xt,
                                               const float* __restrict__ Xv,
                                               u16* __restrict__ Sc)
{
    const int gid = blockIdx.x * 256 + threadIdx.x;   // 32*1024 threads
    const int n = gid >> 10;
    const int c = gid & 1023;
    const size_t PS = (size_t)12800 * 512;            // partial stride

    u16* srow = Sc + (size_t)(n * 400) * 1024 + c;
    srow[0] = 0;   // delay: t=0 is zero

    float buf[8];
    float u = 0.f, v = 0.f;

    if (c < 512) {
        const float* xrow = Xt + (size_t)(n * 400) * 512 + c;
        #pragma unroll
        for (int d = 0; d < 8; ++d) buf[d] = xrow[(size_t)d * 512];
        #pragma unroll 8
        for (int t = 0; t < 400; ++t) {
            const float xt = buf[t & 7];
            const int tn = t + 8;
            buf[t & 7] = (tn < 400) ? xrow[(size_t)tn * 512] : 0.f;
            u = truncf(u * 0.75f) + 64.f * xt;
            v = truncf(v * 0.96875f) + u;
            float sp = 0.f;
            if (v >= 5120.f) { sp = 1.f; v = 0.f; }
            if (t < 399) srow[(size_t)(t + 1) * 1024] = (sp != 0.f) ? (u16)0x3F80 : (u16)0;
        }
    } else {
        const float* xrow = Xv + (size_t)(n * 400) * 512 + (c - 512);
        #pragma unroll
        for (int d = 0; d < 8; ++d) {
            const size_t o = (size_t)d * 512;
            buf[d] = (xrow[o] + xrow[o + PS]) + xrow[o + 2 * PS];
        }
        #pragma unroll 8
        for (int t = 0; t < 400; ++t) {
            const float xt = buf[t & 7];
            const int tn = t + 8;
            float nx = 0.f;
            if (tn < 400) {
                const size_t o = (size_t)tn * 512;
                nx = (xrow[o] + xrow[o + PS]) + xrow[o + 2 * PS];
            }
            buf[t & 7] = nx;
            u = truncf(u * 0.75f) + 64.f * xt;
            v = truncf(v * 0.96875f) + u;
            float sp = 0.f;
            if (v >= 5120.f) { sp = 1.f; v = 0.f; }
            if (t < 399) srow[(size_t)(t + 1) * 1024] = (sp != 0.f) ? (u16)0x3F80 : (u16)0;
        }
    }
}

// scan_c: layer-3 (4 partials) -> output spikes [n][c][t]
__global__ __launch_bounds__(256) void scan_c(const float* __restrict__ Xc,
                                              float* __restrict__ out)
{
    const int gid = blockIdx.x * 256 + threadIdx.x;   // 32*256 threads
    const int n = gid >> 8;
    const int c = gid & 255;
    const size_t PS = (size_t)12800 * 256;            // partial stride
    const float* xrow = Xc + (size_t)(n * 400) * 256 + c;
    float* orow = out + ((size_t)n * 256 + c) * 400;
    orow[0] = 0.f;

    float buf[8];
    #pragma unroll
    for (int d = 0; d < 8; ++d) {
        const size_t o = (size_t)d * 256;
        buf[d] = ((xrow[o] + xrow[o + PS]) + (xrow[o + 2 * PS] + xrow[o + 3 * PS]));
    }
    float u = 0.f, v = 0.f;
    #pragma unroll 8
    for (int t = 0; t < 400; ++t) {
        const float xt = buf[t & 7];
        const int tn = t + 8;
        float nx = 0.f;
        if (tn < 400) {
            const size_t o = (size_t)tn * 256;
            nx = ((xrow[o] + xrow[o + PS]) + (xrow[o + 2 * PS] + xrow[o + 3 * PS]));
        }
        buf[t & 7] = nx;
        u = truncf(u * 0.75f) + 64.f * xt;
        v = truncf(v * 0.96875f) + u;
        float sp = 0.f;
        if (v >= 5120.f) { sp = 1.f; v = 0.f; }
        if (t < 399) orow[t + 1] = sp;
    }
}

extern "C" void kernel_launch(void* const* d_in, const int* in_sizes, int n_in,
                              void* d_out, int out_size, void* d_ws, size_t ws_size,
                              hipStream_t stream)
{
    const float* tact   = (const float*)d_in[0];  // [32][156][400]
    const float* vis    = (const float*)d_in[1];  // [32][6300][400]
    const float* W_tact = (const float*)d_in[2];  // [512][156]
    const float* W_vis  = (const float*)d_in[3];  // [512][6300]
    const float* W_comb = (const float*)d_in[4];  // [256][1024]
    float* out = (float*)d_out;                   // [32][256][400]

    const int NT = 32 * 400;            // 12800
    const int Kt = 156, Ktp = 160;
    const int Kv = 6300, Kvp = 6304;
    const int Kc = 1024;

    // ---- workspace carve-up (bytes, all 256-aligned) ≈ 292 MB peak ----
    char* p = (char*)d_ws;
    u16* Sv = (u16*)p;                 p += (size_t)NT * Kvp * 2;     // 161.4MB
    u16* St = (u16*)p;                 p += (size_t)NT * Ktp * 2;     //   4.1MB
    u16* Wt_h = (u16*)p;               p += (size_t)512 * Ktp * 2;
    u16* Wt_m = (u16*)p;               p += (size_t)512 * Ktp * 2;
    u16* Wt_l = (u16*)p;               p += (size_t)512 * Ktp * 2;
    u16* Wv_h = (u16*)p;               p += (size_t)512 * Kvp * 2;
    u16* Wv_m = (u16*)p;               p += (size_t)512 * Kvp * 2;
    u16* Wv_l = (u16*)p;               p += (size_t)512 * Kvp * 2;
    u16* Wc_h = (u16*)p;               p += (size_t)256 * Kc * 2;
    u16* Wc_m = (u16*)p;               p += (size_t)256 * Kc * 2;
    u16* Wc_l = (u16*)p;               p += (size_t)256 * Kc * 2;
    float* Xt = (float*)p;             p += (size_t)NT * 512 * 4;     //  26.2MB (1 partial)
    float* Xv = (float*)p;             p += (size_t)NT * 512 * 4 * 3; //  78.6MB (3 partials)
    // aliases into dead Sv region (Sv unused after vis gemm3):
    u16*   Sc = Sv;                                 // combi spikes [NT][1024] bf16 (26.2MB)
    float* Xc = (float*)((char*)d_ws + (size_t)NT * 1024 * 2);  // [4][NT][256] f32 (52.4MB)

    // 1) weight splits
    split_w<<<dim3((Ktp + 255) / 256, 512), 256, 0, stream>>>(W_tact, Wt_h, Wt_m, Wt_l, Kt, Ktp);
    split_w<<<dim3((Kvp + 255) / 256, 512), 256, 0, stream>>>(W_vis,  Wv_h, Wv_m, Wv_l, Kv, Kvp);
    split_w<<<dim3((Kc  + 255) / 256, 256), 256, 0, stream>>>(W_comb, Wc_h, Wc_m, Wc_l, Kc, Kc);

    // 2) spike transpose+convert
    cvt_sp<<<dim3(7, (Ktp + 63) / 64, 32), 256, 0, stream>>>(tact, St, Kt, Ktp);
    cvt_sp<<<dim3(7, (Kvp + 63) / 64, 32), 256, 0, stream>>>(vis,  Sv, Kv, Kvp);

    // 3) layer GEMMs (K-split) + scans (sum partials in fixed order)
    gemm3<<<dim3(NT / 128, 512 / 128, 1), 256, 0, stream>>>(Wt_h, Wt_m, Wt_l, St, Xt, 512, Ktp, 5);
    gemm3<<<dim3(NT / 128, 512 / 128, 3), 256, 0, stream>>>(Wv_h, Wv_m, Wv_l, Sv, Xv, 512, Kvp, 66);
    scan_ab<<<dim3((32 * 1024) / 256), 256, 0, stream>>>(Xt, Xv, Sc);
    gemm3<<<dim3(NT / 128, 256 / 128, 4), 256, 0, stream>>>(Wc_h, Wc_m, Wc_l, Sc, Xc, 256, Kc, 8);
    scan_c<<<dim3((32 * 256) / 256), 256, 0, stream>>>(Xc, out);

    (void)in_sizes; (void)n_in; (void)out_size; (void)ws_size;
}

// Round 4
// 799.022 us; speedup vs baseline: 1.0901x; 1.0901x over previous
//
#include <hip/hip_runtime.h>

// Loihi SNN, 3 layers of (GEMM -> Loihi scan -> delay), MFMA edition.
//
// Exact-ish fp32-via-bf16: spikes are {0,1} (exact in bf16); W splits into
// 2 bf16 planes via round-to-nearest (hi = RNE(w), mid = RNE(w - hi), both
// residual subtractions exact). Dropped residual <= 2^-18 |w| -- same
// perturbation class as the fp32 reorder noise already proven safe
// (absmax 0.0 across three different accumulation orders).
//
// Round 4: 2 planes (-33% MFMA work), LDS 24KB (6 blocks/CU), K-split
// kept (vis x3, combi x4) with deterministic partial buffers.
//
// Layouts:
//   S   (GEMM B operand): [nt = n*400+t][Kpad] bf16(u16), contiguous K
//   W2  (GEMM A operand): 2 planes [C][Kpad] bf16(u16)
//   X   (GEMM out):       [z][nt][C] fp32 partials -> scans sum fixed-order
//   out:                  [n][c][t] fp32 (reference layout)

typedef unsigned short u16;
typedef unsigned int u32;
typedef __attribute__((ext_vector_type(8))) short short8;
typedef __attribute__((ext_vector_type(4))) float f32x4;

#define GLOAD16(g, l)                                                         \
    __builtin_amdgcn_global_load_lds(                                         \
        (const __attribute__((address_space(1))) u32*)(g),                    \
        (__attribute__((address_space(3))) u32*)(l), 16, 0, 0)

__device__ __forceinline__ u16 f2bf_trunc(float x) {
    return (u16)(__float_as_uint(x) >> 16);
}

// ---------------- W -> 2 bf16 planes (RNE twofold split) ----------------
__global__ void split_w2(const float* __restrict__ W,
                         u16* __restrict__ Wh, u16* __restrict__ Wm,
                         int K, int Kpad)
{
    const int c = blockIdx.y;
    const int k = blockIdx.x * 256 + threadIdx.x;
    if (k >= Kpad) return;
    float w = (k < K) ? W[(size_t)c * K + k] : 0.f;
    u32 b  = __float_as_uint(w);
    u32 hb = (b + 0x7FFFu + ((b >> 16) & 1u)) & 0xFFFF0000u;  // RNE bf16
    float r = w - __uint_as_float(hb);                         // exact
    u32 rb = __float_as_uint(r);
    u32 mb = (rb + 0x7FFFu + ((rb >> 16) & 1u)) & 0xFFFF0000u; // RNE bf16
    size_t o = (size_t)c * Kpad + k;
    Wh[o] = (u16)(hb >> 16);
    Wm[o] = (u16)(mb >> 16);
}

// ------- spikes fp32 [n][I][400] -> bf16 [n*400+t][Kpad] (transpose) -------
__global__ __launch_bounds__(256) void cvt_sp(const float* __restrict__ S,
                                              u16* __restrict__ Sp,
                                              int I, int Kpad)
{
    __shared__ u16 tile[64][80];   // [t][i], stride 160B (16B-aligned rows)
    const int n  = blockIdx.z;
    const int i0 = blockIdx.y * 64;
    const int t0 = blockIdx.x * 64;
    const int tid = threadIdx.x;

    const int il = tid >> 2;       // 0..63 input row (i)
    const int tq = tid & 3;
    const int gi = i0 + il;
    const bool iok = gi < I;
    const float* srow = S + ((size_t)n * I + gi) * 400 + t0;

    #pragma unroll
    for (int s = 0; s < 4; ++s) {
        const int tl = tq * 16 + s * 4;
        float4 v = make_float4(0.f, 0.f, 0.f, 0.f);
        if (iok && (t0 + tl) < 400)
            v = *(const float4*)(srow + tl);
        tile[tl + 0][il] = f2bf_trunc(v.x);
        tile[tl + 1][il] = f2bf_trunc(v.y);
        tile[tl + 2][il] = f2bf_trunc(v.z);
        tile[tl + 3][il] = f2bf_trunc(v.w);
    }
    __syncthreads();

    const int tl = tid >> 2;       // 0..63 output row (t)
    const int iq = tid & 3;        // 16-wide i chunk
    const int t  = t0 + tl;
    const int go = i0 + iq * 16;
    if (t < 400 && go < Kpad) {
        u16* dst = Sp + (size_t)(n * 400 + t) * Kpad + go;
        *(short8*)(dst)     = *(const short8*)&tile[tl][iq * 16];
        *(short8*)(dst + 8) = *(const short8*)&tile[tl][iq * 16 + 8];
    }
}

// ---------------- 2-plane bf16 MFMA GEMM, K-split ----------------
// Xp[z][nt][c] = sum_{k in chunk z} (Wh+Wm)[c][k] * S[nt][k]
// 128x128 tile, BK=32, 4 waves (2x2), wave = 64x64 = 4x4 MFMA tiles.
__global__ __launch_bounds__(256) void gemm3(
    const u16* __restrict__ Wh, const u16* __restrict__ Wm,
    const u16* __restrict__ S,
    float* __restrict__ Xp, int C, int Kpad, int chunkIters)
{
    __shared__ u16 lds[3 * 4096];   // A planes 0..1, B at 2*4096 ([128][32] each)

    const int tid  = threadIdx.x;
    const int lane = tid & 63, wave = tid >> 6;
    const int c0  = blockIdx.y * 128;
    const int nt0 = blockIdx.x * 128;
    const int NT  = gridDim.x * 128;

    const int kz0 = blockIdx.z * chunkIters * 32;
    const int kz1 = min(Kpad, kz0 + chunkIters * 32);
    float* __restrict__ X = Xp + (size_t)blockIdx.z * NT * C;

    // staging: per wave 2 chunks per tile; chunk = 16 rows x 32 k (1KB)
    const int ch0 = wave * 2, ch1 = ch0 + 1;
    const int lrow = lane >> 2;          // row within chunk
    const int lk   = (lane & 3) * 8;     // u16 offset within row
    const size_t aoff0 = (size_t)(c0 + ch0 * 16 + lrow) * Kpad + lk;
    const size_t aoff1 = (size_t)(c0 + ch1 * 16 + lrow) * Kpad + lk;
    const size_t boff0 = (size_t)(nt0 + ch0 * 16 + lrow) * Kpad + lk;
    const size_t boff1 = (size_t)(nt0 + ch1 * 16 + lrow) * Kpad + lk;

    const int l15 = lane & 15, l16 = lane >> 4;
    const int wm = wave >> 1, wn = wave & 1;
    const int aBase = (wm * 64 + l15) * 32 + l16 * 8;            // + p*4096 + mi*512
    const int bBase = 2 * 4096 + (wn * 64 + l15) * 32 + l16 * 8; // + ni*512

    f32x4 acc[4][4];
    #pragma unroll
    for (int i = 0; i < 4; ++i)
        #pragma unroll
        for (int j = 0; j < 4; ++j)
            acc[i][j] = {0.f, 0.f, 0.f, 0.f};

    for (int k0 = kz0; k0 < kz1; k0 += 32) {
        GLOAD16(Wh + aoff0 + k0, &lds[0 * 4096 + ch0 * 512]);
        GLOAD16(Wh + aoff1 + k0, &lds[0 * 4096 + ch1 * 512]);
        GLOAD16(Wm + aoff0 + k0, &lds[1 * 4096 + ch0 * 512]);
        GLOAD16(Wm + aoff1 + k0, &lds[1 * 4096 + ch1 * 512]);
        GLOAD16(S  + boff0 + k0, &lds[2 * 4096 + ch0 * 512]);
        GLOAD16(S  + boff1 + k0, &lds[2 * 4096 + ch1 * 512]);
        __syncthreads();   // drains vmcnt -> staged data visible

        short8 bf[4];
        #pragma unroll
        for (int ni = 0; ni < 4; ++ni)
            bf[ni] = *(const short8*)&lds[bBase + ni * 512];
        #pragma unroll
        for (int mi = 0; mi < 4; ++mi) {
            const short8 a0 = *(const short8*)&lds[0 * 4096 + aBase + mi * 512];
            const short8 a1 = *(const short8*)&lds[1 * 4096 + aBase + mi * 512];
            #pragma unroll
            for (int ni = 0; ni < 4; ++ni) {
                acc[mi][ni] = __builtin_amdgcn_mfma_f32_16x16x32_bf16(
                    a0, bf[ni], acc[mi][ni], 0, 0, 0);
                acc[mi][ni] = __builtin_amdgcn_mfma_f32_16x16x32_bf16(
                    a1, bf[ni], acc[mi][ni], 0, 0, 0);
            }
        }
        __syncthreads();   // readers done before next overwrite
    }

    // epilogue: D row=(l16*4+r) -> c, col=l15 -> nt ; 4 consecutive c = float4
    #pragma unroll
    for (int mi = 0; mi < 4; ++mi) {
        const int c = c0 + wm * 64 + mi * 16 + l16 * 4;
        #pragma unroll
        for (int ni = 0; ni < 4; ++ni) {
            const int nt = nt0 + wn * 64 + ni * 16 + l15;
            *(f32x4*)&X[(size_t)nt * C + c] = acc[mi][ni];
        }
    }
}

// ---------------- Loihi scans (8-deep pipelined loads) ----------------
// scan_ab: layer-1 tact (1 partial) + layer-1 vis (3 partials) -> combi spikes
__global__ __launch_bounds__(256) void scan_ab(const float* __restrict__ Xt,
                                               const float* __restrict__ Xv,
                                               u16* __restrict__ Sc)
{
    const int gid = blockIdx.x * 256 + threadIdx.x;   // 32*1024 threads
    const int n = gid >> 10;
    const int c = gid & 1023;
    const size_t PS = (size_t)12800 * 512;            // partial stride

    u16* srow = Sc + (size_t)(n * 400) * 1024 + c;
    srow[0] = 0;   // delay: t=0 is zero

    float buf[8];
    float u = 0.f, v = 0.f;

    if (c < 512) {
        const float* xrow = Xt + (size_t)(n * 400) * 512 + c;
        #pragma unroll
        for (int d = 0; d < 8; ++d) buf[d] = xrow[(size_t)d * 512];
        #pragma unroll 8
        for (int t = 0; t < 400; ++t) {
            const float xt = buf[t & 7];
            const int tn = t + 8;
            buf[t & 7] = (tn < 400) ? xrow[(size_t)tn * 512] : 0.f;
            u = truncf(u * 0.75f) + 64.f * xt;
            v = truncf(v * 0.96875f) + u;
            float sp = 0.f;
            if (v >= 5120.f) { sp = 1.f; v = 0.f; }
            if (t < 399) srow[(size_t)(t + 1) * 1024] = (sp != 0.f) ? (u16)0x3F80 : (u16)0;
        }
    } else {
        const float* xrow = Xv + (size_t)(n * 400) * 512 + (c - 512);
        #pragma unroll
        for (int d = 0; d < 8; ++d) {
            const size_t o = (size_t)d * 512;
            buf[d] = (xrow[o] + xrow[o + PS]) + xrow[o + 2 * PS];
        }
        #pragma unroll 8
        for (int t = 0; t < 400; ++t) {
            const float xt = buf[t & 7];
            const int tn = t + 8;
            float nx = 0.f;
            if (tn < 400) {
                const size_t o = (size_t)tn * 512;
                nx = (xrow[o] + xrow[o + PS]) + xrow[o + 2 * PS];
            }
            buf[t & 7] = nx;
            u = truncf(u * 0.75f) + 64.f * xt;
            v = truncf(v * 0.96875f) + u;
            float sp = 0.f;
            if (v >= 5120.f) { sp = 1.f; v = 0.f; }
            if (t < 399) srow[(size_t)(t + 1) * 1024] = (sp != 0.f) ? (u16)0x3F80 : (u16)0;
        }
    }
}

// scan_c: layer-3 (4 partials) -> output spikes [n][c][t]
__global__ __launch_bounds__(256) void scan_c(const float* __restrict__ Xc,
                                              float* __restrict__ out)
{
    const int gid = blockIdx.x * 256 + threadIdx.x;   // 32*256 threads
    const int n = gid >> 8;
    const int c = gid & 255;
    const size_t PS = (size_t)12800 * 256;            // partial stride
    const float* xrow = Xc + (size_t)(n * 400) * 256 + c;
    float* orow = out + ((size_t)n * 256 + c) * 400;
    orow[0] = 0.f;

    float buf[8];
    #pragma unroll
    for (int d = 0; d < 8; ++d) {
        const size_t o = (size_t)d * 256;
        buf[d] = ((xrow[o] + xrow[o + PS]) + (xrow[o + 2 * PS] + xrow[o + 3 * PS]));
    }
    float u = 0.f, v = 0.f;
    #pragma unroll 8
    for (int t = 0; t < 400; ++t) {
        const float xt = buf[t & 7];
        const int tn = t + 8;
        float nx = 0.f;
        if (tn < 400) {
            const size_t o = (size_t)tn * 256;
            nx = ((xrow[o] + xrow[o + PS]) + (xrow[o + 2 * PS] + xrow[o + 3 * PS]));
        }
        buf[t & 7] = nx;
        u = truncf(u * 0.75f) + 64.f * xt;
        v = truncf(v * 0.96875f) + u;
        float sp = 0.f;
        if (v >= 5120.f) { sp = 1.f; v = 0.f; }
        if (t < 399) orow[t + 1] = sp;
    }
}

extern "C" void kernel_launch(void* const* d_in, const int* in_sizes, int n_in,
                              void* d_out, int out_size, void* d_ws, size_t ws_size,
                              hipStream_t stream)
{
    const float* tact   = (const float*)d_in[0];  // [32][156][400]
    const float* vis    = (const float*)d_in[1];  // [32][6300][400]
    const float* W_tact = (const float*)d_in[2];  // [512][156]
    const float* W_vis  = (const float*)d_in[3];  // [512][6300]
    const float* W_comb = (const float*)d_in[4];  // [256][1024]
    float* out = (float*)d_out;                   // [32][256][400]

    const int NT = 32 * 400;            // 12800
    const int Kt = 156, Ktp = 160;
    const int Kv = 6300, Kvp = 6304;
    const int Kc = 1024;

    // ---- workspace carve-up (bytes, all 256-aligned) ≈ 285 MB peak ----
    char* p = (char*)d_ws;
    u16* Sv = (u16*)p;                 p += (size_t)NT * Kvp * 2;     // 161.4MB
    u16* St = (u16*)p;                 p += (size_t)NT * Ktp * 2;     //   4.1MB
    u16* Wt_h = (u16*)p;               p += (size_t)512 * Ktp * 2;
    u16* Wt_m = (u16*)p;               p += (size_t)512 * Ktp * 2;
    u16* Wv_h = (u16*)p;               p += (size_t)512 * Kvp * 2;
    u16* Wv_m = (u16*)p;               p += (size_t)512 * Kvp * 2;
    u16* Wc_h = (u16*)p;               p += (size_t)256 * Kc * 2;
    u16* Wc_m = (u16*)p;               p += (size_t)256 * Kc * 2;
    float* Xt = (float*)p;             p += (size_t)NT * 512 * 4;     //  26.2MB (1 partial)
    float* Xv = (float*)p;             p += (size_t)NT * 512 * 4 * 3; //  78.6MB (3 partials)
    // aliases into dead Sv region (Sv unused after vis gemm3):
    u16*   Sc = Sv;                                 // combi spikes [NT][1024] bf16 (26.2MB)
    float* Xc = (float*)((char*)d_ws + (size_t)NT * 1024 * 2);  // [4][NT][256] f32 (52.4MB)

    // 1) weight splits (2 RNE planes)
    split_w2<<<dim3((Ktp + 255) / 256, 512), 256, 0, stream>>>(W_tact, Wt_h, Wt_m, Kt, Ktp);
    split_w2<<<dim3((Kvp + 255) / 256, 512), 256, 0, stream>>>(W_vis,  Wv_h, Wv_m, Kv, Kvp);
    split_w2<<<dim3((Kc  + 255) / 256, 256), 256, 0, stream>>>(W_comb, Wc_h, Wc_m, Kc, Kc);

    // 2) spike transpose+convert
    cvt_sp<<<dim3(7, (Ktp + 63) / 64, 32), 256, 0, stream>>>(tact, St, Kt, Ktp);
    cvt_sp<<<dim3(7, (Kvp + 63) / 64, 32), 256, 0, stream>>>(vis,  Sv, Kv, Kvp);

    // 3) layer GEMMs (K-split) + scans (sum partials in fixed order)
    gemm3<<<dim3(NT / 128, 512 / 128, 1), 256, 0, stream>>>(Wt_h, Wt_m, St, Xt, 512, Ktp, 5);
    gemm3<<<dim3(NT / 128, 512 / 128, 3), 256, 0, stream>>>(Wv_h, Wv_m, Sv, Xv, 512, Kvp, 66);
    scan_ab<<<dim3((32 * 1024) / 256), 256, 0, stream>>>(Xt, Xv, Sc);
    gemm3<<<dim3(NT / 128, 256 / 128, 4), 256, 0, stream>>>(Wc_h, Wc_m, Sc, Xc, 256, Kc, 8);
    scan_c<<<dim3((32 * 256) / 256), 256, 0, stream>>>(Xc, out);

    (void)in_sizes; (void)n_in; (void)out_size; (void)ws_size;
}

// Round 5
// 599.057 us; speedup vs baseline: 1.4540x; 1.3338x over previous
//
#include <hip/hip_runtime.h>

// Loihi SNN, 3 layers of (GEMM -> Loihi scan -> delay), MFMA edition.
//
// Numerics: spikes {0,1} exact in bf16; W split into 2 RNE bf16 planes
// (hi = RNE(w), mid = RNE(w-hi)); dropped residual <= 2^-18|w| -- proven
// safe (absmax 0.0 in rounds 2-4 across multiple accumulation orders).
//
// Round 5: pipeline-breadth fixes.
//  - gemm __launch_bounds__(256,4): 4 blocks/CU (was unified-VGPR capped ~3)
//  - tact GEMM fused into vis GEMM launch (blockIdx.z==3)
//  - vis partials pre-reduced in-place (wide grid) before scan_ab
//  - scans: 64-thread blocks (all CUs active) + depth-16 load pipelines
//  - combi GEMM z=2, scan_c reads 2 partials
//
// Layouts:
//   S   (GEMM B operand): [nt = n*400+t][Kpad] bf16(u16), contiguous K
//   W2  (GEMM A operand): 2 planes [C][Kpad] bf16(u16)
//   X   (GEMM out):       [z][nt][C] fp32 partials
//   out:                  [n][c][t] fp32 (reference layout)

typedef unsigned short u16;
typedef unsigned int u32;
typedef __attribute__((ext_vector_type(8))) short short8;
typedef __attribute__((ext_vector_type(4))) float f32x4;

#define GLOAD16(g, l)                                                         \
    __builtin_amdgcn_global_load_lds(                                         \
        (const __attribute__((address_space(1))) u32*)(g),                    \
        (__attribute__((address_space(3))) u32*)(l), 16, 0, 0)

__device__ __forceinline__ u16 f2bf_trunc(float x) {
    return (u16)(__float_as_uint(x) >> 16);
}

// ---------------- W -> 2 bf16 planes (RNE twofold split) ----------------
__global__ void split_w2(const float* __restrict__ W,
                         u16* __restrict__ Wh, u16* __restrict__ Wm,
                         int K, int Kpad)
{
    const int c = blockIdx.y;
    const int k = blockIdx.x * 256 + threadIdx.x;
    if (k >= Kpad) return;
    float w = (k < K) ? W[(size_t)c * K + k] : 0.f;
    u32 b  = __float_as_uint(w);
    u32 hb = (b + 0x7FFFu + ((b >> 16) & 1u)) & 0xFFFF0000u;  // RNE bf16
    float r = w - __uint_as_float(hb);                         // exact
    u32 rb = __float_as_uint(r);
    u32 mb = (rb + 0x7FFFu + ((rb >> 16) & 1u)) & 0xFFFF0000u; // RNE bf16
    size_t o = (size_t)c * Kpad + k;
    Wh[o] = (u16)(hb >> 16);
    Wm[o] = (u16)(mb >> 16);
}

// ------- spikes fp32 [n][I][400] -> bf16 [n*400+t][Kpad] (transpose) -------
__global__ __launch_bounds__(256) void cvt_sp(const float* __restrict__ S,
                                              u16* __restrict__ Sp,
                                              int I, int Kpad)
{
    __shared__ u16 tile[64][80];   // [t][i], stride 160B (16B-aligned rows)
    const int n  = blockIdx.z;
    const int i0 = blockIdx.y * 64;
    const int t0 = blockIdx.x * 64;
    const int tid = threadIdx.x;

    const int il = tid >> 2;       // 0..63 input row (i)
    const int tq = tid & 3;
    const int gi = i0 + il;
    const bool iok = gi < I;
    const float* srow = S + ((size_t)n * I + gi) * 400 + t0;

    #pragma unroll
    for (int s = 0; s < 4; ++s) {
        const int tl = tq * 16 + s * 4;
        float4 v = make_float4(0.f, 0.f, 0.f, 0.f);
        if (iok && (t0 + tl) < 400)
            v = *(const float4*)(srow + tl);
        tile[tl + 0][il] = f2bf_trunc(v.x);
        tile[tl + 1][il] = f2bf_trunc(v.y);
        tile[tl + 2][il] = f2bf_trunc(v.z);
        tile[tl + 3][il] = f2bf_trunc(v.w);
    }
    __syncthreads();

    const int tl = tid >> 2;       // 0..63 output row (t)
    const int iq = tid & 3;        // 16-wide i chunk
    const int t  = t0 + tl;
    const int go = i0 + iq * 16;
    if (t < 400 && go < Kpad) {
        u16* dst = Sp + (size_t)(n * 400 + t) * Kpad + go;
        *(short8*)(dst)     = *(const short8*)&tile[tl][iq * 16];
        *(short8*)(dst + 8) = *(const short8*)&tile[tl][iq * 16 + 8];
    }
}

// ---------------- 2-plane bf16 MFMA GEMM body ----------------
// X[nt][c] += (over k in [kz0,kz1)) (Wh+Wm)[c][k] * S[nt][k]
// 128x128 tile, BK=32, 4 waves (2x2), wave = 64x64 = 4x4 MFMA tiles.
__device__ __forceinline__ void gemm_body(
    const u16* __restrict__ Wh, const u16* __restrict__ Wm,
    const u16* __restrict__ S, float* __restrict__ X,
    int C, int Kpad, int kz0, int kz1, u16* lds)
{
    const int tid  = threadIdx.x;
    const int lane = tid & 63, wave = tid >> 6;
    const int c0  = blockIdx.y * 128;
    const int nt0 = blockIdx.x * 128;

    // staging: per wave 2 chunks per tile; chunk = 16 rows x 32 k (1KB)
    const int ch0 = wave * 2, ch1 = ch0 + 1;
    const int lrow = lane >> 2;          // row within chunk
    const int lk   = (lane & 3) * 8;     // u16 offset within row
    const size_t aoff0 = (size_t)(c0 + ch0 * 16 + lrow) * Kpad + lk;
    const size_t aoff1 = (size_t)(c0 + ch1 * 16 + lrow) * Kpad + lk;
    const size_t boff0 = (size_t)(nt0 + ch0 * 16 + lrow) * Kpad + lk;
    const size_t boff1 = (size_t)(nt0 + ch1 * 16 + lrow) * Kpad + lk;

    const int l15 = lane & 15, l16 = lane >> 4;
    const int wm = wave >> 1, wn = wave & 1;
    const int aBase = (wm * 64 + l15) * 32 + l16 * 8;            // + p*4096 + mi*512
    const int bBase = 2 * 4096 + (wn * 64 + l15) * 32 + l16 * 8; // + ni*512

    f32x4 acc[4][4];
    #pragma unroll
    for (int i = 0; i < 4; ++i)
        #pragma unroll
        for (int j = 0; j < 4; ++j)
            acc[i][j] = {0.f, 0.f, 0.f, 0.f};

    for (int k0 = kz0; k0 < kz1; k0 += 32) {
        GLOAD16(Wh + aoff0 + k0, &lds[0 * 4096 + ch0 * 512]);
        GLOAD16(Wh + aoff1 + k0, &lds[0 * 4096 + ch1 * 512]);
        GLOAD16(Wm + aoff0 + k0, &lds[1 * 4096 + ch0 * 512]);
        GLOAD16(Wm + aoff1 + k0, &lds[1 * 4096 + ch1 * 512]);
        GLOAD16(S  + boff0 + k0, &lds[2 * 4096 + ch0 * 512]);
        GLOAD16(S  + boff1 + k0, &lds[2 * 4096 + ch1 * 512]);
        __syncthreads();   // drains vmcnt -> staged data visible

        short8 bf[4];
        #pragma unroll
        for (int ni = 0; ni < 4; ++ni)
            bf[ni] = *(const short8*)&lds[bBase + ni * 512];
        #pragma unroll
        for (int mi = 0; mi < 4; ++mi) {
            const short8 a0 = *(const short8*)&lds[0 * 4096 + aBase + mi * 512];
            const short8 a1 = *(const short8*)&lds[1 * 4096 + aBase + mi * 512];
            #pragma unroll
            for (int ni = 0; ni < 4; ++ni) {
                acc[mi][ni] = __builtin_amdgcn_mfma_f32_16x16x32_bf16(
                    a0, bf[ni], acc[mi][ni], 0, 0, 0);
                acc[mi][ni] = __builtin_amdgcn_mfma_f32_16x16x32_bf16(
                    a1, bf[ni], acc[mi][ni], 0, 0, 0);
            }
        }
        __syncthreads();   // readers done before next overwrite
    }

    // epilogue: D row=(l16*4+r) -> c, col=l15 -> nt ; 4 consecutive c = float4
    #pragma unroll
    for (int mi = 0; mi < 4; ++mi) {
        const int c = c0 + wm * 64 + mi * 16 + l16 * 4;
        #pragma unroll
        for (int ni = 0; ni < 4; ++ni) {
            const int nt = nt0 + wn * 64 + ni * 16 + l15;
            *(f32x4*)&X[(size_t)nt * C + c] = acc[mi][ni];
        }
    }
}

// layer-1 fused: z=0..2 -> vis K-chunks, z=3 -> tact (full K). C=512 both.
__global__ __launch_bounds__(256, 4) void gemm_l1(
    const u16* __restrict__ Wvh, const u16* __restrict__ Wvm,
    const u16* __restrict__ Sv, float* __restrict__ Xv, int Kvp, int vIters,
    const u16* __restrict__ Wth, const u16* __restrict__ Wtm,
    const u16* __restrict__ St, float* __restrict__ Xt, int Ktp)
{
    __shared__ u16 lds[3 * 4096];   // 24 KB
    const int z = blockIdx.z;
    if (z < 3) {
        const int kz0 = z * vIters * 32;
        const int kz1 = min(Kvp, kz0 + vIters * 32);
        gemm_body(Wvh, Wvm, Sv, Xv + (size_t)z * 12800 * 512, 512, Kvp, kz0, kz1, lds);
    } else {
        gemm_body(Wth, Wtm, St, Xt, 512, Ktp, 0, Ktp, lds);
    }
}

// layer-3: combi GEMM, z=0..1 K-chunks of 512. C=256.
__global__ __launch_bounds__(256, 4) void gemm_l3(
    const u16* __restrict__ Wh, const u16* __restrict__ Wm,
    const u16* __restrict__ S, float* __restrict__ Xp)
{
    __shared__ u16 lds[3 * 4096];
    const int kz0 = blockIdx.z * 512;
    gemm_body(Wh, Wm, S, Xp + (size_t)blockIdx.z * 12800 * 256,
              256, 1024, kz0, kz0 + 512, lds);
}

// ---------------- vis partial pre-reduce (in place: Xv0 = (Xv0+Xv1)+Xv2) ---
__global__ __launch_bounds__(256) void reduce3(float* __restrict__ X)
{
    const size_t PS4 = (size_t)12800 * 512 / 4;   // float4 per partial
    f32x4* p = (f32x4*)X;
    for (size_t i = (size_t)blockIdx.x * 256 + threadIdx.x; i < PS4;
         i += (size_t)gridDim.x * 256) {
        f32x4 a = p[i], b = p[i + PS4], c = p[i + 2 * PS4];
        p[i] = (a + b) + c;
    }
}

// ---------------- Loihi scans (depth-16 pipelined loads, 64-thr blocks) ----
// scan_ab: layer-1 tact + vis (pre-reduced) -> combi spikes [nt][1024] bf16
__global__ __launch_bounds__(64) void scan_ab(const float* __restrict__ Xt,
                                              const float* __restrict__ Xv,
                                              u16* __restrict__ Sc)
{
    const int gid = blockIdx.x * 64 + threadIdx.x;   // 32*1024 threads
    const int n = gid >> 10;
    const int c = gid & 1023;
    const float* xrow = (c < 512)
        ? Xt + (size_t)(n * 400) * 512 + c
        : Xv + (size_t)(n * 400) * 512 + (c - 512);
    u16* srow = Sc + (size_t)(n * 400) * 1024 + c;
    srow[0] = 0;   // delay: t=0 is zero

    float buf[16];
    #pragma unroll
    for (int d = 0; d < 16; ++d) buf[d] = xrow[(size_t)d * 512];
    float u = 0.f, v = 0.f;
    #pragma unroll 16
    for (int t = 0; t < 400; ++t) {
        const float xt = buf[t & 15];
        const int tn = t + 16;
        buf[t & 15] = (tn < 400) ? xrow[(size_t)tn * 512] : 0.f;
        u = truncf(u * 0.75f) + 64.f * xt;
        v = truncf(v * 0.96875f) + u;
        float sp = 0.f;
        if (v >= 5120.f) { sp = 1.f; v = 0.f; }
        if (t < 399) srow[(size_t)(t + 1) * 1024] = (sp != 0.f) ? (u16)0x3F80 : (u16)0;
    }
}

// scan_c: layer-3 (2 partials) -> output spikes [n][c][t]
__global__ __launch_bounds__(64) void scan_c(const float* __restrict__ Xc,
                                             float* __restrict__ out)
{
    const int gid = blockIdx.x * 64 + threadIdx.x;   // 32*256 threads
    const int n = gid >> 8;
    const int c = gid & 255;
    const size_t PS = (size_t)12800 * 256;            // partial stride
    const float* xrow = Xc + (size_t)(n * 400) * 256 + c;
    float* orow = out + ((size_t)n * 256 + c) * 400;
    orow[0] = 0.f;

    float buf[16];
    #pragma unroll
    for (int d = 0; d < 16; ++d) {
        const size_t o = (size_t)d * 256;
        buf[d] = xrow[o] + xrow[o + PS];
    }
    float u = 0.f, v = 0.f;
    #pragma unroll 16
    for (int t = 0; t < 400; ++t) {
        const float xt = buf[t & 15];
        const int tn = t + 16;
        float nx = 0.f;
        if (tn < 400) {
            const size_t o = (size_t)tn * 256;
            nx = xrow[o] + xrow[o + PS];
        }
        buf[t & 15] = nx;
        u = truncf(u * 0.75f) + 64.f * xt;
        v = truncf(v * 0.96875f) + u;
        float sp = 0.f;
        if (v >= 5120.f) { sp = 1.f; v = 0.f; }
        if (t < 399) orow[t + 1] = sp;
    }
}

extern "C" void kernel_launch(void* const* d_in, const int* in_sizes, int n_in,
                              void* d_out, int out_size, void* d_ws, size_t ws_size,
                              hipStream_t stream)
{
    const float* tact   = (const float*)d_in[0];  // [32][156][400]
    const float* vis    = (const float*)d_in[1];  // [32][6300][400]
    const float* W_tact = (const float*)d_in[2];  // [512][156]
    const float* W_vis  = (const float*)d_in[3];  // [512][6300]
    const float* W_comb = (const float*)d_in[4];  // [256][1024]
    float* out = (float*)d_out;                   // [32][256][400]

    const int NT = 32 * 400;            // 12800
    const int Kt = 156, Ktp = 160;
    const int Kv = 6300, Kvp = 6304;
    const int Kc = 1024;

    // ---- workspace carve-up (bytes, all 256-aligned) ≈ 285 MB peak ----
    char* p = (char*)d_ws;
    u16* Sv = (u16*)p;                 p += (size_t)NT * Kvp * 2;     // 161.4MB
    u16* St = (u16*)p;                 p += (size_t)NT * Ktp * 2;     //   4.1MB
    u16* Wt_h = (u16*)p;               p += (size_t)512 * Ktp * 2;
    u16* Wt_m = (u16*)p;               p += (size_t)512 * Ktp * 2;
    u16* Wv_h = (u16*)p;               p += (size_t)512 * Kvp * 2;
    u16* Wv_m = (u16*)p;               p += (size_t)512 * Kvp * 2;
    u16* Wc_h = (u16*)p;               p += (size_t)256 * Kc * 2;
    u16* Wc_m = (u16*)p;               p += (size_t)256 * Kc * 2;
    float* Xt = (float*)p;             p += (size_t)NT * 512 * 4;     //  26.2MB (1 partial)
    float* Xv = (float*)p;             p += (size_t)NT * 512 * 4 * 3; //  78.6MB (3 partials)
    // aliases into dead Sv region (Sv unused after layer-1 gemm):
    u16*   Sc = Sv;                                             // [NT][1024] bf16 (26.2MB)
    float* Xc = (float*)((char*)d_ws + (size_t)NT * 1024 * 2);  // [2][NT][256] f32 (26.2MB)

    // 1) weight splits (2 RNE planes)
    split_w2<<<dim3((Ktp + 255) / 256, 512), 256, 0, stream>>>(W_tact, Wt_h, Wt_m, Kt, Ktp);
    split_w2<<<dim3((Kvp + 255) / 256, 512), 256, 0, stream>>>(W_vis,  Wv_h, Wv_m, Kv, Kvp);
    split_w2<<<dim3((Kc  + 255) / 256, 256), 256, 0, stream>>>(W_comb, Wc_h, Wc_m, Kc, Kc);

    // 2) spike transpose+convert
    cvt_sp<<<dim3(7, (Ktp + 63) / 64, 32), 256, 0, stream>>>(tact, St, Kt, Ktp);
    cvt_sp<<<dim3(7, (Kvp + 63) / 64, 32), 256, 0, stream>>>(vis,  Sv, Kv, Kvp);

    // 3) layer-1 GEMMs fused (vis z=0..2 K-chunks of 66 iters, tact z=3)
    gemm_l1<<<dim3(NT / 128, 512 / 128, 4), 256, 0, stream>>>(
        Wv_h, Wv_m, Sv, Xv, Kvp, 66, Wt_h, Wt_m, St, Xt, Ktp);

    // 4) pre-reduce vis partials in place, then scan layer 1+2 -> combi spikes
    reduce3<<<dim3(2048), 256, 0, stream>>>(Xv);
    scan_ab<<<dim3((32 * 1024) / 64), 64, 0, stream>>>(Xt, Xv, Sc);

    // 5) layer-3 GEMM (z=2 K-chunks of 512) + scan -> out
    gemm_l3<<<dim3(NT / 128, 256 / 128, 2), 256, 0, stream>>>(Wc_h, Wc_m, Sc, Xc);
    scan_c<<<dim3((32 * 256) / 64), 64, 0, stream>>>(Xc, out);

    (void)in_sizes; (void)n_in; (void)out_size; (void)ws_size;
}